// Round 2
// baseline (848.769 us; speedup 1.0000x reference)
//
#include <hip/hip_runtime.h>
#include <cmath>

#define NN 200000
#define EE 6400000
#define NBKT 391          // ceil(200000 / 512), bucket = col >> 9
#define GRID_A 512        // blocks in phase-A kernels (MUST match scan width)
#define BLK_A 256
#define RB_SHIFT 13       // row band = row >> 13 (8192 rows/band)
#define NRB 25            // ceil(200000 / 8192)

// =============== Phase A: bucket edges by col>>9 (counting sort, LDS atomics only) ===============

// A1: per-block LDS histogram of buckets (int4 edge loads: 4 edges/lane/iter)
__global__ __launch_bounds__(BLK_A) void count_buckets_kernel(const int* __restrict__ col,
                                                              int* __restrict__ blkhist) {
    __shared__ int h[NBKT];
    for (int t = threadIdx.x; t < NBKT; t += BLK_A) h[t] = 0;
    __syncthreads();
    const int4* col4 = (const int4*)col;
    for (int i = blockIdx.x * BLK_A + threadIdx.x; i < EE / 4; i += GRID_A * BLK_A) {
        int4 c = col4[i];
        atomicAdd(&h[c.x >> 9], 1);
        atomicAdd(&h[c.y >> 9], 1);
        atomicAdd(&h[c.z >> 9], 1);
        atomicAdd(&h[c.w >> 9], 1);
    }
    __syncthreads();
    for (int t = threadIdx.x; t < NBKT; t += BLK_A) blkhist[blockIdx.x * NBKT + t] = h[t];
}

__global__ __launch_bounds__(GRID_A) void scan_cols_kernel(int* __restrict__ blkhist,
                                                           int* __restrict__ btot) {
    __shared__ int sc[GRID_A];
    int bkt = blockIdx.x, t = threadIdx.x;
    int v = blkhist[t * NBKT + bkt];
    sc[t] = v;
    __syncthreads();
    for (int off = 1; off < GRID_A; off <<= 1) {
        int add = (t >= off) ? sc[t - off] : 0;
        __syncthreads();
        sc[t] += add;
        __syncthreads();
    }
    blkhist[t * NBKT + bkt] = sc[t] - v;  // exclusive along blocks
    if (t == GRID_A - 1) btot[bkt] = sc[t];
}

__global__ __launch_bounds__(512) void scan_btot_kernel(const int* __restrict__ btot,
                                                        int* __restrict__ bbase) {
    __shared__ int sc[512];
    int t = threadIdx.x;
    int v = (t < NBKT) ? btot[t] : 0;
    sc[t] = v;
    __syncthreads();
    for (int off = 1; off < 512; off <<= 1) {
        int add = (t >= off) ? sc[t - off] : 0;
        __syncthreads();
        sc[t] += add;
        __syncthreads();
    }
    if (t < NBKT) bbase[t] = sc[t] - v;
    if (t == NBKT - 1) bbase[NBKT] = sc[t];  // total = EE
}

// A3: place packed codes (int4 edge loads). code = (col&511)<<18 | row  (row < 2^18)
__global__ __launch_bounds__(BLK_A) void place_pairs_kernel(const int* __restrict__ row,
                                                            const int* __restrict__ col,
                                                            const int* __restrict__ blkhist,
                                                            const int* __restrict__ bbase,
                                                            unsigned int* __restrict__ pairs) {
    __shared__ int cur[NBKT];
    for (int t = threadIdx.x; t < NBKT; t += BLK_A)
        cur[t] = bbase[t] + blkhist[blockIdx.x * NBKT + t];
    __syncthreads();
    const int4* col4 = (const int4*)col;
    const int4* row4 = (const int4*)row;
    for (int i = blockIdx.x * BLK_A + threadIdx.x; i < EE / 4; i += GRID_A * BLK_A) {
        int4 c = col4[i];
        int4 r = row4[i];
        int p0 = atomicAdd(&cur[c.x >> 9], 1);
        pairs[p0] = (unsigned int)r.x | ((unsigned int)(c.x & 511) << 18);
        int p1 = atomicAdd(&cur[c.y >> 9], 1);
        pairs[p1] = (unsigned int)r.y | ((unsigned int)(c.y & 511) << 18);
        int p2 = atomicAdd(&cur[c.z >> 9], 1);
        pairs[p2] = (unsigned int)r.z | ((unsigned int)(c.z & 511) << 18);
        int p3 = atomicAdd(&cur[c.w >> 9], 1);
        pairs[p3] = (unsigned int)r.w | ((unsigned int)(c.w & 511) << 18);
    }
}

// A4: per-bucket (localcol x rowband) counting sort.
// Adjacency of each node comes out grouped by row>>RB_SHIFT (ascending bands) so
// the gather kernels can sweep y in row-band phases and keep the hot band in L2.
__global__ __launch_bounds__(512) void bucket_build_kernel(const unsigned int* __restrict__ pairs,
                                                           const int* __restrict__ bbase,
                                                           int* __restrict__ deg,
                                                           int* __restrict__ offs,
                                                           float* __restrict__ dinv,
                                                           int* __restrict__ row_sorted) {
    __shared__ int h2[512 * NRB];   // 51.2 KB: per (localcol, band) counters -> cursors
    __shared__ int sc[512];
    int b = blockIdx.x, tid = threadIdx.x;
    int base = bbase[b], end = bbase[b + 1];
    int node0 = b << 9;
    int nloc = NN - node0; if (nloc > 512) nloc = 512;

    for (int t = tid; t < 512 * NRB; t += 512) h2[t] = 0;
    __syncthreads();
    for (int i = base + tid; i < end; i += 512) {
        unsigned int p = pairs[i];
        atomicAdd(&h2[(p >> 18) * NRB + ((p & 0x3FFFFu) >> RB_SHIFT)], 1);
    }
    __syncthreads();

    // per-node serial exclusive scan over its NRB bins; acc = node degree
    int acc = 0;
    for (int r = 0; r < NRB; ++r) {
        int c = h2[tid * NRB + r];
        h2[tid * NRB + r] = acc;
        acc += c;
    }
    sc[tid] = acc;
    __syncthreads();
    for (int off = 1; off < 512; off <<= 1) {
        int add = (tid >= off) ? sc[tid - off] : 0;
        __syncthreads();
        sc[tid] += add;
        __syncthreads();
    }
    int excl = sc[tid] - acc;

    if (tid < nloc) {
        deg[node0 + tid]  = acc;
        offs[node0 + tid] = base + excl;
        dinv[node0 + tid] = rsqrtf((float)(acc + 1));  // +1 self loop
    }
    for (int r = 0; r < NRB; ++r) h2[tid * NRB + r] += base + excl;   // bin cursors
    __syncthreads();

    for (int i = base + tid; i < end; i += 512) {
        unsigned int p = pairs[i];
        int rw = (int)(p & 0x3FFFFu);
        int pos = atomicAdd(&h2[(p >> 18) * NRB + (rw >> RB_SHIFT)], 1);
        row_sorted[pos] = rw;
    }
}

// =============== layer-1 matmul, epilogue premultiplies dinv: y = dinv[i] * (x[i] @ W) ===============
__global__ void matmul128_y_kernel(const float* __restrict__ x, const float* __restrict__ W,
                                   const float* __restrict__ dinv, float* __restrict__ y, int n) {
    __shared__ float Ws[128 * 24];
    for (int t = threadIdx.x; t < 128 * 24; t += blockDim.x) Ws[t] = W[t];
    __syncthreads();
    int i = blockIdx.x * blockDim.x + threadIdx.x;
    if (i >= n) return;
    float acc[24];
#pragma unroll
    for (int j = 0; j < 24; ++j) acc[j] = 0.f;
    const float4* hr = (const float4*)(x + (size_t)i * 128);
#pragma unroll 8
    for (int k4 = 0; k4 < 32; ++k4) {
        float4 hv = hr[k4];
        const float* wk = &Ws[k4 * 4 * 24];
#pragma unroll
        for (int j = 0; j < 24; ++j) acc[j] += hv.x * wk[j];
#pragma unroll
        for (int j = 0; j < 24; ++j) acc[j] += hv.y * wk[24 + j];
#pragma unroll
        for (int j = 0; j < 24; ++j) acc[j] += hv.z * wk[48 + j];
#pragma unroll
        for (int j = 0; j < 24; ++j) acc[j] += hv.w * wk[72 + j];
    }
    float di = dinv[i];
    float4* orow = (float4*)(y + (size_t)i * 24);
#pragma unroll
    for (int q = 0; q < 6; ++q) {
        float4 o;
        o.x = di * acc[q * 4 + 0];
        o.y = di * acc[q * 4 + 1];
        o.z = di * acc[q * 4 + 2];
        o.w = di * acc[q * 4 + 3];
        orow[q] = o;
    }
}

// =============== fused gather-max-tanh + next matmul, row-band phased for L2 locality ===============
// Adjacency is band-sorted (row>>RB_SHIFT ascending). All blocks sweep bands in
// program order with a block barrier per band: at any instant the chip reads a
// ~0.8-3 MB slice of y, which stays resident in every XCD's L2.
template<int DOUT, int DNEXT, int VEC>
__global__ __launch_bounds__(256) void gather_fused_kernel(const int* __restrict__ offs,
                                                           const int* __restrict__ deg,
                                                           const int* __restrict__ row_sorted,
                                                           const float* __restrict__ dinv,
                                                           const float* __restrict__ y,
                                                           const float* __restrict__ b,
                                                           const float* __restrict__ Wn,
                                                           float* __restrict__ ynext) {
    constexpr int LPN = DOUT / VEC;        // lanes per node
    constexpr int NPB = 256 / LPN;         // nodes per block
    typedef float vec_t __attribute__((ext_vector_type(VEC)));

    __shared__ float hs[NPB * DOUT];
    __shared__ float dcs[NPB];

    int ln = threadIdx.x / LPN;
    int j  = threadIdx.x % LPN;
    int node = blockIdx.x * NPB + ln;
    bool active = (ln < NPB) && (node < NN);

    const vec_t* yv = (const vec_t*)y;
    vec_t m;
#pragma unroll
    for (int c = 0; c < VEC; ++c) m[c] = 0.f;
    float dc = 0.f;
    int k = 0, e = 0;
    int curRow = 0x7FFFFFFF;

    if (active) {
        dc = dinv[node];
        m = yv[(size_t)node * LPN + j];   // self-loop seed (y already has dinv_self)
        k = offs[node];
        e = k + deg[node];
        if (k < e) curRow = row_sorted[k];
    }

    for (int rb = 0; rb < NRB; ++rb) {
        int bend = (rb + 1) << RB_SHIFT;
        while (curRow < bend) {
            vec_t v = yv[(size_t)curRow * LPN + j];
            ++k;
            int nr = (k < e) ? row_sorted[k] : 0x7FFFFFFF;
#pragma unroll
            for (int c = 0; c < VEC; ++c) m[c] = fmaxf(m[c], v[c]);
            curRow = nr;
        }
        __syncthreads();   // keep all waves of the block in the same row band
    }

    if (active) {
#pragma unroll
        for (int c = 0; c < VEC; ++c)
            hs[ln * DOUT + j * VEC + c] = tanhf(dc * m[c] + b[j * VEC + c]);
        if (j == 0) dcs[ln] = dc;
    }
    __syncthreads();

    // phase 2: y_next = dc * (h @ Wn) for the staged nodes
    for (int idx = threadIdx.x; idx < NPB * DNEXT; idx += 256) {
        int ln2 = idx / DNEXT;
        int j2 = idx - ln2 * DNEXT;
        int gn = blockIdx.x * NPB + ln2;
        if (gn < NN) {
            float acc = 0.f;
#pragma unroll
            for (int k2 = 0; k2 < DOUT; ++k2) acc += hs[ln2 * DOUT + k2] * Wn[k2 * DNEXT + j2];
            ynext[(size_t)gn * DNEXT + j2] = dcs[ln2] * acc;
        }
    }
}

// =============== layer 4 (DOUT=4): whole row in one thread, no LDS, 8x unrolled ===============
// y4 = 3.2 MB -> already fits per-XCD L2; no phasing needed.
__global__ __launch_bounds__(256) void gather_fused4_kernel(const int* __restrict__ offs,
                                                            const int* __restrict__ deg,
                                                            const int* __restrict__ row_sorted,
                                                            const float* __restrict__ dinv,
                                                            const float* __restrict__ y,
                                                            const float* __restrict__ b,
                                                            const float* __restrict__ Wn,   // 4x2
                                                            float* __restrict__ ynext) {
    int node = blockIdx.x * 256 + threadIdx.x;
    if (node >= NN) return;
    float dc = dinv[node];
    const float4* yv = (const float4*)y;
    float4 m = yv[node];
    int s = offs[node];
    int e = s + deg[node];
    int k = s;
    for (; k + 7 < e; k += 8) {
        int r[8];
#pragma unroll
        for (int u = 0; u < 8; ++u) r[u] = row_sorted[k + u];
        float4 v[8];
#pragma unroll
        for (int u = 0; u < 8; ++u) v[u] = yv[r[u]];
        float ax, ay, az, aw, bx, by, bz, bw;
        ax = fmaxf(fmaxf(v[0].x, v[1].x), fmaxf(v[2].x, v[3].x));
        bx = fmaxf(fmaxf(v[4].x, v[5].x), fmaxf(v[6].x, v[7].x));
        ay = fmaxf(fmaxf(v[0].y, v[1].y), fmaxf(v[2].y, v[3].y));
        by = fmaxf(fmaxf(v[4].y, v[5].y), fmaxf(v[6].y, v[7].y));
        az = fmaxf(fmaxf(v[0].z, v[1].z), fmaxf(v[2].z, v[3].z));
        bz = fmaxf(fmaxf(v[4].z, v[5].z), fmaxf(v[6].z, v[7].z));
        aw = fmaxf(fmaxf(v[0].w, v[1].w), fmaxf(v[2].w, v[3].w));
        bw = fmaxf(fmaxf(v[4].w, v[5].w), fmaxf(v[6].w, v[7].w));
        m.x = fmaxf(m.x, fmaxf(ax, bx));
        m.y = fmaxf(m.y, fmaxf(ay, by));
        m.z = fmaxf(m.z, fmaxf(az, bz));
        m.w = fmaxf(m.w, fmaxf(aw, bw));
    }
    for (; k + 3 < e; k += 4) {
        float4 v0 = yv[row_sorted[k]];
        float4 v1 = yv[row_sorted[k + 1]];
        float4 v2 = yv[row_sorted[k + 2]];
        float4 v3 = yv[row_sorted[k + 3]];
        m.x = fmaxf(m.x, fmaxf(fmaxf(v0.x, v1.x), fmaxf(v2.x, v3.x)));
        m.y = fmaxf(m.y, fmaxf(fmaxf(v0.y, v1.y), fmaxf(v2.y, v3.y)));
        m.z = fmaxf(m.z, fmaxf(fmaxf(v0.z, v1.z), fmaxf(v2.z, v3.z)));
        m.w = fmaxf(m.w, fmaxf(fmaxf(v0.w, v1.w), fmaxf(v2.w, v3.w)));
    }
    for (; k < e; ++k) {
        float4 v0 = yv[row_sorted[k]];
        m.x = fmaxf(m.x, v0.x); m.y = fmaxf(m.y, v0.y);
        m.z = fmaxf(m.z, v0.z); m.w = fmaxf(m.w, v0.w);
    }
    float h0 = tanhf(dc * m.x + b[0]);
    float h1 = tanhf(dc * m.y + b[1]);
    float h2 = tanhf(dc * m.z + b[2]);
    float h3 = tanhf(dc * m.w + b[3]);
    float2 o;
    o.x = dc * (h0 * Wn[0] + h1 * Wn[2] + h2 * Wn[4] + h3 * Wn[6]);
    o.y = dc * (h0 * Wn[1] + h1 * Wn[3] + h2 * Wn[5] + h3 * Wn[7]);
    ((float2*)ynext)[node] = o;
}

// =============== layer 5 (DOUT=2) + classifier, no LDS, 8x unrolled ===============
__global__ __launch_bounds__(256) void gather_final_kernel(const int* __restrict__ offs,
                                                           const int* __restrict__ deg,
                                                           const int* __restrict__ row_sorted,
                                                           const float* __restrict__ dinv,
                                                           const float* __restrict__ y,
                                                           const float* __restrict__ b,
                                                           const float* __restrict__ Wc,  // 2x4
                                                           const float* __restrict__ bc,
                                                           float* __restrict__ out,
                                                           float* __restrict__ hout) {
    int node = blockIdx.x * 256 + threadIdx.x;
    if (node >= NN) return;
    float dc = dinv[node];
    const float2* yv = (const float2*)y;
    float2 m = yv[node];
    int s = offs[node];
    int e = s + deg[node];
    int k = s;
    for (; k + 7 < e; k += 8) {
        int r[8];
#pragma unroll
        for (int u = 0; u < 8; ++u) r[u] = row_sorted[k + u];
        float2 v[8];
#pragma unroll
        for (int u = 0; u < 8; ++u) v[u] = yv[r[u]];
        float ax = fmaxf(fmaxf(v[0].x, v[1].x), fmaxf(v[2].x, v[3].x));
        float bx = fmaxf(fmaxf(v[4].x, v[5].x), fmaxf(v[6].x, v[7].x));
        float ay = fmaxf(fmaxf(v[0].y, v[1].y), fmaxf(v[2].y, v[3].y));
        float by = fmaxf(fmaxf(v[4].y, v[5].y), fmaxf(v[6].y, v[7].y));
        m.x = fmaxf(m.x, fmaxf(ax, bx));
        m.y = fmaxf(m.y, fmaxf(ay, by));
    }
    for (; k + 3 < e; k += 4) {
        float2 v0 = yv[row_sorted[k]];
        float2 v1 = yv[row_sorted[k + 1]];
        float2 v2 = yv[row_sorted[k + 2]];
        float2 v3 = yv[row_sorted[k + 3]];
        m.x = fmaxf(m.x, fmaxf(fmaxf(v0.x, v1.x), fmaxf(v2.x, v3.x)));
        m.y = fmaxf(m.y, fmaxf(fmaxf(v0.y, v1.y), fmaxf(v2.y, v3.y)));
    }
    for (; k < e; ++k) {
        float2 v0 = yv[row_sorted[k]];
        m.x = fmaxf(m.x, v0.x); m.y = fmaxf(m.y, v0.y);
    }
    float h0 = tanhf(dc * m.x + b[0]);
    float h1 = tanhf(dc * m.y + b[1]);
    float2 ho; ho.x = h0; ho.y = h1;
    ((float2*)hout)[node] = ho;
    float4 o;
    o.x = h0 * Wc[0] + h1 * Wc[4] + bc[0];
    o.y = h0 * Wc[1] + h1 * Wc[5] + bc[1];
    o.z = h0 * Wc[2] + h1 * Wc[6] + bc[2];
    o.w = h0 * Wc[3] + h1 * Wc[7] + bc[3];
    ((float4*)out)[node] = o;
}

extern "C" void kernel_launch(void* const* d_in, const int* in_sizes, int n_in,
                              void* d_out, int out_size, void* d_ws, size_t ws_size,
                              hipStream_t stream) {
    const float* x  = (const float*)d_in[0];
    const int*   ei = (const int*)d_in[1];
    const int* row = ei;            // edge_index[0] = source
    const int* col = ei + EE;       // edge_index[1] = target
    const float* W1 = (const float*)d_in[2];  const float* b1 = (const float*)d_in[3];
    const float* W2 = (const float*)d_in[4];  const float* b2 = (const float*)d_in[5];
    const float* W3 = (const float*)d_in[6];  const float* b3 = (const float*)d_in[7];
    const float* W4 = (const float*)d_in[8];  const float* b4 = (const float*)d_in[9];
    const float* W5 = (const float*)d_in[10]; const float* b5 = (const float*)d_in[11];
    const float* Wc = (const float*)d_in[12]; const float* bc = (const float*)d_in[13];
    float* out = (float*)d_out;

    // ---- workspace carve ----
    // pairs (25.6 MB) is dead before matmul128_y writes bufB -> alias them.
    char* ws = (char*)d_ws;
    int*          deg        = (int*)(ws + 0);          //    800,000
    float*        dinv       = (float*)(ws + 800000);   //    800,000
    int*          offs       = (int*)(ws + 1600000);    //    800,000
    int*          bbase      = (int*)(ws + 2400000);    //      2,048  (NBKT+1 ints)
    int*          blkhist    = (int*)(ws + 2402048);    //    802,816  (GRID_A*NBKT ints)
    int*          btot       = (int*)(ws + 3204864);    //      2,048
    unsigned int* pairs      = (unsigned int*)(ws + 3206912);   // 25,600,000
    float*        bufB       = (float*)(ws + 3206912);          // 25,600,000 (aliases pairs; y1/y3/y5)
    int*          row_sorted = (int*)(ws + 28806912);           // 25,600,000
    float*        bufA       = (float*)(ws + 54406912);         // 19,200,000 (y2/y4)
    // total: 73,606,912 B

    const int BLK = 256;
    const int gN = (NN + BLK - 1) / BLK;       // 782

    // ---- CSR build: two-level counting sort, LDS atomics only; adjacency band-sorted ----
    count_buckets_kernel<<<GRID_A, BLK_A, 0, stream>>>(col, blkhist);
    scan_cols_kernel<<<NBKT, GRID_A, 0, stream>>>(blkhist, btot);
    scan_btot_kernel<<<1, 512, 0, stream>>>(btot, bbase);
    place_pairs_kernel<<<GRID_A, BLK_A, 0, stream>>>(row, col, blkhist, bbase, pairs);
    bucket_build_kernel<<<NBKT, 512, 0, stream>>>(pairs, bbase, deg, offs, dinv, row_sorted);

    // ---- layer 1 matmul: y1 = dinv * (x @ W1), [N,24] ----
    matmul128_y_kernel<<<gN, BLK, 0, stream>>>(x, W1, dinv, bufB, NN);

    // ---- layer 1 gather + layer-2 matmul fused: y2 [N,12] ----
    {
        constexpr int NPB = 256 / (24 / 4);   // 42 nodes/block
        gather_fused_kernel<24, 12, 4><<<(NN + NPB - 1) / NPB, 256, 0, stream>>>(
            offs, deg, row_sorted, dinv, bufB, b1, W2, bufA);
    }
    // ---- layer 2 gather + layer-3 matmul fused: y3 [N,6] ----
    {
        constexpr int NPB = 256 / (12 / 4);   // 85 nodes/block
        gather_fused_kernel<12, 6, 4><<<(NN + NPB - 1) / NPB, 256, 0, stream>>>(
            offs, deg, row_sorted, dinv, bufA, b2, W3, bufB);
    }
    // ---- layer 3 gather + layer-4 matmul fused: y4 [N,4] ----
    {
        constexpr int NPB = 256 / (6 / 2);    // 85 nodes/block
        gather_fused_kernel<6, 4, 2><<<(NN + NPB - 1) / NPB, 256, 0, stream>>>(
            offs, deg, row_sorted, dinv, bufB, b3, W4, bufA);
    }
    // ---- layer 4 gather + layer-5 matmul fused: y5 [N,2] ----
    gather_fused4_kernel<<<gN, BLK, 0, stream>>>(offs, deg, row_sorted, dinv, bufA, b4, W5, bufB);

    // ---- layer 5 gather + classifier fused: out [N,4], h [N,2] ----
    gather_final_kernel<<<gN, BLK, 0, stream>>>(offs, deg, row_sorted, dinv, bufB, b5, Wc, bc,
                                                out, out + (size_t)NN * 4);
}

// Round 3
// 789.293 us; speedup vs baseline: 1.0754x; 1.0754x over previous
//
#include <hip/hip_runtime.h>
#include <cmath>

#define NN 200000
#define EE 6400000
#define NBKT 391          // ceil(200000 / 512), bucket = col >> 9
#define GRID_A 512        // blocks in phase-A kernels (MUST match scan width)
#define BLK_A 256
#define RB_SHIFT 13       // row band = row >> 13 (8192 rows/band)
#define NRB 25            // ceil(200000 / 8192)

// =============== Phase A: bucket edges by col>>9 (counting sort, LDS atomics only) ===============

// A1: per-block LDS histogram of buckets (int4 edge loads: 4 edges/lane/iter)
__global__ __launch_bounds__(BLK_A) void count_buckets_kernel(const int* __restrict__ col,
                                                              int* __restrict__ blkhist) {
    __shared__ int h[NBKT];
    for (int t = threadIdx.x; t < NBKT; t += BLK_A) h[t] = 0;
    __syncthreads();
    const int4* col4 = (const int4*)col;
    for (int i = blockIdx.x * BLK_A + threadIdx.x; i < EE / 4; i += GRID_A * BLK_A) {
        int4 c = col4[i];
        atomicAdd(&h[c.x >> 9], 1);
        atomicAdd(&h[c.y >> 9], 1);
        atomicAdd(&h[c.z >> 9], 1);
        atomicAdd(&h[c.w >> 9], 1);
    }
    __syncthreads();
    for (int t = threadIdx.x; t < NBKT; t += BLK_A) blkhist[blockIdx.x * NBKT + t] = h[t];
}

__global__ __launch_bounds__(GRID_A) void scan_cols_kernel(int* __restrict__ blkhist,
                                                           int* __restrict__ btot) {
    __shared__ int sc[GRID_A];
    int bkt = blockIdx.x, t = threadIdx.x;
    int v = blkhist[t * NBKT + bkt];
    sc[t] = v;
    __syncthreads();
    for (int off = 1; off < GRID_A; off <<= 1) {
        int add = (t >= off) ? sc[t - off] : 0;
        __syncthreads();
        sc[t] += add;
        __syncthreads();
    }
    blkhist[t * NBKT + bkt] = sc[t] - v;  // exclusive along blocks
    if (t == GRID_A - 1) btot[bkt] = sc[t];
}

__global__ __launch_bounds__(512) void scan_btot_kernel(const int* __restrict__ btot,
                                                        int* __restrict__ bbase) {
    __shared__ int sc[512];
    int t = threadIdx.x;
    int v = (t < NBKT) ? btot[t] : 0;
    sc[t] = v;
    __syncthreads();
    for (int off = 1; off < 512; off <<= 1) {
        int add = (t >= off) ? sc[t - off] : 0;
        __syncthreads();
        sc[t] += add;
        __syncthreads();
    }
    if (t < NBKT) bbase[t] = sc[t] - v;
    if (t == NBKT - 1) bbase[NBKT] = sc[t];  // total = EE
}

// A3: place packed codes (int4 edge loads). code = (col&511)<<18 | row  (row < 2^18)
__global__ __launch_bounds__(BLK_A) void place_pairs_kernel(const int* __restrict__ row,
                                                            const int* __restrict__ col,
                                                            const int* __restrict__ blkhist,
                                                            const int* __restrict__ bbase,
                                                            unsigned int* __restrict__ pairs) {
    __shared__ int cur[NBKT];
    for (int t = threadIdx.x; t < NBKT; t += BLK_A)
        cur[t] = bbase[t] + blkhist[blockIdx.x * NBKT + t];
    __syncthreads();
    const int4* col4 = (const int4*)col;
    const int4* row4 = (const int4*)row;
    for (int i = blockIdx.x * BLK_A + threadIdx.x; i < EE / 4; i += GRID_A * BLK_A) {
        int4 c = col4[i];
        int4 r = row4[i];
        int p0 = atomicAdd(&cur[c.x >> 9], 1);
        pairs[p0] = (unsigned int)r.x | ((unsigned int)(c.x & 511) << 18);
        int p1 = atomicAdd(&cur[c.y >> 9], 1);
        pairs[p1] = (unsigned int)r.y | ((unsigned int)(c.y & 511) << 18);
        int p2 = atomicAdd(&cur[c.z >> 9], 1);
        pairs[p2] = (unsigned int)r.z | ((unsigned int)(c.z & 511) << 18);
        int p3 = atomicAdd(&cur[c.w >> 9], 1);
        pairs[p3] = (unsigned int)r.w | ((unsigned int)(c.w & 511) << 18);
    }
}

// A4: per-bucket (localcol x rowband) counting sort.
// Adjacency of each node comes out grouped by row>>RB_SHIFT (ascending bands):
// gathers then sweep y in ascending order, statistically keeping co-resident
// blocks inside the same ~0.8 MB y-slice (L2-resident) without any barriers.
__global__ __launch_bounds__(512) void bucket_build_kernel(const unsigned int* __restrict__ pairs,
                                                           const int* __restrict__ bbase,
                                                           int* __restrict__ deg,
                                                           int* __restrict__ offs,
                                                           float* __restrict__ dinv,
                                                           int* __restrict__ row_sorted) {
    __shared__ int h2[512 * NRB];   // 51.2 KB: per (localcol, band) counters -> cursors
    __shared__ int sc[512];
    int b = blockIdx.x, tid = threadIdx.x;
    int base = bbase[b], end = bbase[b + 1];
    int node0 = b << 9;
    int nloc = NN - node0; if (nloc > 512) nloc = 512;

    for (int t = tid; t < 512 * NRB; t += 512) h2[t] = 0;
    __syncthreads();
    for (int i = base + tid; i < end; i += 512) {
        unsigned int p = pairs[i];
        atomicAdd(&h2[(p >> 18) * NRB + ((p & 0x3FFFFu) >> RB_SHIFT)], 1);
    }
    __syncthreads();

    // per-node serial exclusive scan over its NRB bins; acc = node degree
    int acc = 0;
    for (int r = 0; r < NRB; ++r) {
        int c = h2[tid * NRB + r];
        h2[tid * NRB + r] = acc;
        acc += c;
    }
    sc[tid] = acc;
    __syncthreads();
    for (int off = 1; off < 512; off <<= 1) {
        int add = (tid >= off) ? sc[tid - off] : 0;
        __syncthreads();
        sc[tid] += add;
        __syncthreads();
    }
    int excl = sc[tid] - acc;

    if (tid < nloc) {
        deg[node0 + tid]  = acc;
        offs[node0 + tid] = base + excl;
        dinv[node0 + tid] = rsqrtf((float)(acc + 1));  // +1 self loop
    }
    for (int r = 0; r < NRB; ++r) h2[tid * NRB + r] += base + excl;   // bin cursors
    __syncthreads();

    for (int i = base + tid; i < end; i += 512) {
        unsigned int p = pairs[i];
        int rw = (int)(p & 0x3FFFFu);
        int pos = atomicAdd(&h2[(p >> 18) * NRB + (rw >> RB_SHIFT)], 1);
        row_sorted[pos] = rw;
    }
}

// =============== layer-1 matmul, epilogue premultiplies dinv: y = dinv[i] * (x[i] @ W) ===============
__global__ void matmul128_y_kernel(const float* __restrict__ x, const float* __restrict__ W,
                                   const float* __restrict__ dinv, float* __restrict__ y, int n) {
    __shared__ float Ws[128 * 24];
    for (int t = threadIdx.x; t < 128 * 24; t += blockDim.x) Ws[t] = W[t];
    __syncthreads();
    int i = blockIdx.x * blockDim.x + threadIdx.x;
    if (i >= n) return;
    float acc[24];
#pragma unroll
    for (int j = 0; j < 24; ++j) acc[j] = 0.f;
    const float4* hr = (const float4*)(x + (size_t)i * 128);
#pragma unroll 8
    for (int k4 = 0; k4 < 32; ++k4) {
        float4 hv = hr[k4];
        const float* wk = &Ws[k4 * 4 * 24];
#pragma unroll
        for (int j = 0; j < 24; ++j) acc[j] += hv.x * wk[j];
#pragma unroll
        for (int j = 0; j < 24; ++j) acc[j] += hv.y * wk[24 + j];
#pragma unroll
        for (int j = 0; j < 24; ++j) acc[j] += hv.z * wk[48 + j];
#pragma unroll
        for (int j = 0; j < 24; ++j) acc[j] += hv.w * wk[72 + j];
    }
    float di = dinv[i];
    float4* orow = (float4*)(y + (size_t)i * 24);
#pragma unroll
    for (int q = 0; q < 6; ++q) {
        float4 o;
        o.x = di * acc[q * 4 + 0];
        o.y = di * acc[q * 4 + 1];
        o.z = di * acc[q * 4 + 2];
        o.w = di * acc[q * 4 + 3];
        orow[q] = o;
    }
}

// =============== fused gather-max-tanh + next matmul (LDS h staging), 8x unrolled ===============
// Adjacency is band-sorted (ascending source rows) -> the 8-deep MLP loop sweeps
// y in ascending order: L2 locality without barriers, 8 loads in flight.
template<int DOUT, int DNEXT, int VEC>
__global__ __launch_bounds__(256) void gather_fused_kernel(const int* __restrict__ offs,
                                                           const int* __restrict__ deg,
                                                           const int* __restrict__ row_sorted,
                                                           const float* __restrict__ dinv,
                                                           const float* __restrict__ y,
                                                           const float* __restrict__ b,
                                                           const float* __restrict__ Wn,
                                                           float* __restrict__ ynext) {
    constexpr int LPN = DOUT / VEC;        // lanes per node
    constexpr int NPB = 256 / LPN;         // nodes per block
    typedef float vec_t __attribute__((ext_vector_type(VEC)));

    __shared__ float hs[NPB * DOUT];
    __shared__ float dcs[NPB];

    int ln = threadIdx.x / LPN;
    int j  = threadIdx.x % LPN;
    int node = blockIdx.x * NPB + ln;
    bool active = (ln < NPB) && (node < NN);

    if (active) {
        float dc = dinv[node];
        const vec_t* yv = (const vec_t*)y;
        vec_t m = yv[(size_t)node * LPN + j];   // self-loop seed (y already has dinv_self)
        int s = offs[node];
        int e = s + deg[node];
        int k = s;
        for (; k + 7 < e; k += 8) {            // 8 independent loads in flight
            int r[8];
#pragma unroll
            for (int u = 0; u < 8; ++u) r[u] = row_sorted[k + u];
            vec_t v[8];
#pragma unroll
            for (int u = 0; u < 8; ++u) v[u] = yv[(size_t)r[u] * LPN + j];
#pragma unroll
            for (int c = 0; c < VEC; ++c) {
                float a0 = fmaxf(fmaxf(v[0][c], v[1][c]), fmaxf(v[2][c], v[3][c]));
                float a1 = fmaxf(fmaxf(v[4][c], v[5][c]), fmaxf(v[6][c], v[7][c]));
                m[c] = fmaxf(m[c], fmaxf(a0, a1));
            }
        }
        for (; k + 3 < e; k += 4) {
            int r0 = row_sorted[k];
            int r1 = row_sorted[k + 1];
            int r2 = row_sorted[k + 2];
            int r3 = row_sorted[k + 3];
            vec_t v0 = yv[(size_t)r0 * LPN + j];
            vec_t v1 = yv[(size_t)r1 * LPN + j];
            vec_t v2 = yv[(size_t)r2 * LPN + j];
            vec_t v3 = yv[(size_t)r3 * LPN + j];
#pragma unroll
            for (int c = 0; c < VEC; ++c)
                m[c] = fmaxf(m[c], fmaxf(fmaxf(v0[c], v1[c]), fmaxf(v2[c], v3[c])));
        }
        for (; k < e; ++k) {
            vec_t v0 = yv[(size_t)row_sorted[k] * LPN + j];
#pragma unroll
            for (int c = 0; c < VEC; ++c) m[c] = fmaxf(m[c], v0[c]);
        }
#pragma unroll
        for (int c = 0; c < VEC; ++c)
            hs[ln * DOUT + j * VEC + c] = tanhf(dc * m[c] + b[j * VEC + c]);
        if (j == 0) dcs[ln] = dc;
    }
    __syncthreads();

    // phase 2: y_next = dc * (h @ Wn) for the staged nodes
    for (int idx = threadIdx.x; idx < NPB * DNEXT; idx += 256) {
        int ln2 = idx / DNEXT;
        int j2 = idx - ln2 * DNEXT;
        int gn = blockIdx.x * NPB + ln2;
        if (gn < NN) {
            float acc = 0.f;
#pragma unroll
            for (int k2 = 0; k2 < DOUT; ++k2) acc += hs[ln2 * DOUT + k2] * Wn[k2 * DNEXT + j2];
            ynext[(size_t)gn * DNEXT + j2] = dcs[ln2] * acc;
        }
    }
}

// =============== layer 4 (DOUT=4): whole row in one thread, no LDS, 8x unrolled ===============
// y4 = 3.2 MB -> fits per-XCD L2 outright.
__global__ __launch_bounds__(256) void gather_fused4_kernel(const int* __restrict__ offs,
                                                            const int* __restrict__ deg,
                                                            const int* __restrict__ row_sorted,
                                                            const float* __restrict__ dinv,
                                                            const float* __restrict__ y,
                                                            const float* __restrict__ b,
                                                            const float* __restrict__ Wn,   // 4x2
                                                            float* __restrict__ ynext) {
    int node = blockIdx.x * 256 + threadIdx.x;
    if (node >= NN) return;
    float dc = dinv[node];
    const float4* yv = (const float4*)y;
    float4 m = yv[node];
    int s = offs[node];
    int e = s + deg[node];
    int k = s;
    for (; k + 7 < e; k += 8) {
        int r[8];
#pragma unroll
        for (int u = 0; u < 8; ++u) r[u] = row_sorted[k + u];
        float4 v[8];
#pragma unroll
        for (int u = 0; u < 8; ++u) v[u] = yv[r[u]];
        float ax, ay, az, aw, bx, by, bz, bw;
        ax = fmaxf(fmaxf(v[0].x, v[1].x), fmaxf(v[2].x, v[3].x));
        bx = fmaxf(fmaxf(v[4].x, v[5].x), fmaxf(v[6].x, v[7].x));
        ay = fmaxf(fmaxf(v[0].y, v[1].y), fmaxf(v[2].y, v[3].y));
        by = fmaxf(fmaxf(v[4].y, v[5].y), fmaxf(v[6].y, v[7].y));
        az = fmaxf(fmaxf(v[0].z, v[1].z), fmaxf(v[2].z, v[3].z));
        bz = fmaxf(fmaxf(v[4].z, v[5].z), fmaxf(v[6].z, v[7].z));
        aw = fmaxf(fmaxf(v[0].w, v[1].w), fmaxf(v[2].w, v[3].w));
        bw = fmaxf(fmaxf(v[4].w, v[5].w), fmaxf(v[6].w, v[7].w));
        m.x = fmaxf(m.x, fmaxf(ax, bx));
        m.y = fmaxf(m.y, fmaxf(ay, by));
        m.z = fmaxf(m.z, fmaxf(az, bz));
        m.w = fmaxf(m.w, fmaxf(aw, bw));
    }
    for (; k + 3 < e; k += 4) {
        float4 v0 = yv[row_sorted[k]];
        float4 v1 = yv[row_sorted[k + 1]];
        float4 v2 = yv[row_sorted[k + 2]];
        float4 v3 = yv[row_sorted[k + 3]];
        m.x = fmaxf(m.x, fmaxf(fmaxf(v0.x, v1.x), fmaxf(v2.x, v3.x)));
        m.y = fmaxf(m.y, fmaxf(fmaxf(v0.y, v1.y), fmaxf(v2.y, v3.y)));
        m.z = fmaxf(m.z, fmaxf(fmaxf(v0.z, v1.z), fmaxf(v2.z, v3.z)));
        m.w = fmaxf(m.w, fmaxf(fmaxf(v0.w, v1.w), fmaxf(v2.w, v3.w)));
    }
    for (; k < e; ++k) {
        float4 v0 = yv[row_sorted[k]];
        m.x = fmaxf(m.x, v0.x); m.y = fmaxf(m.y, v0.y);
        m.z = fmaxf(m.z, v0.z); m.w = fmaxf(m.w, v0.w);
    }
    float h0 = tanhf(dc * m.x + b[0]);
    float h1 = tanhf(dc * m.y + b[1]);
    float h2 = tanhf(dc * m.z + b[2]);
    float h3 = tanhf(dc * m.w + b[3]);
    float2 o;
    o.x = dc * (h0 * Wn[0] + h1 * Wn[2] + h2 * Wn[4] + h3 * Wn[6]);
    o.y = dc * (h0 * Wn[1] + h1 * Wn[3] + h2 * Wn[5] + h3 * Wn[7]);
    ((float2*)ynext)[node] = o;
}

// =============== layer 5 (DOUT=2) + classifier, no LDS, 8x unrolled ===============
__global__ __launch_bounds__(256) void gather_final_kernel(const int* __restrict__ offs,
                                                           const int* __restrict__ deg,
                                                           const int* __restrict__ row_sorted,
                                                           const float* __restrict__ dinv,
                                                           const float* __restrict__ y,
                                                           const float* __restrict__ b,
                                                           const float* __restrict__ Wc,  // 2x4
                                                           const float* __restrict__ bc,
                                                           float* __restrict__ out,
                                                           float* __restrict__ hout) {
    int node = blockIdx.x * 256 + threadIdx.x;
    if (node >= NN) return;
    float dc = dinv[node];
    const float2* yv = (const float2*)y;
    float2 m = yv[node];
    int s = offs[node];
    int e = s + deg[node];
    int k = s;
    for (; k + 7 < e; k += 8) {
        int r[8];
#pragma unroll
        for (int u = 0; u < 8; ++u) r[u] = row_sorted[k + u];
        float2 v[8];
#pragma unroll
        for (int u = 0; u < 8; ++u) v[u] = yv[r[u]];
        float ax = fmaxf(fmaxf(v[0].x, v[1].x), fmaxf(v[2].x, v[3].x));
        float bx = fmaxf(fmaxf(v[4].x, v[5].x), fmaxf(v[6].x, v[7].x));
        float ay = fmaxf(fmaxf(v[0].y, v[1].y), fmaxf(v[2].y, v[3].y));
        float by = fmaxf(fmaxf(v[4].y, v[5].y), fmaxf(v[6].y, v[7].y));
        m.x = fmaxf(m.x, fmaxf(ax, bx));
        m.y = fmaxf(m.y, fmaxf(ay, by));
    }
    for (; k + 3 < e; k += 4) {
        float2 v0 = yv[row_sorted[k]];
        float2 v1 = yv[row_sorted[k + 1]];
        float2 v2 = yv[row_sorted[k + 2]];
        float2 v3 = yv[row_sorted[k + 3]];
        m.x = fmaxf(m.x, fmaxf(fmaxf(v0.x, v1.x), fmaxf(v2.x, v3.x)));
        m.y = fmaxf(m.y, fmaxf(fmaxf(v0.y, v1.y), fmaxf(v2.y, v3.y)));
    }
    for (; k < e; ++k) {
        float2 v0 = yv[row_sorted[k]];
        m.x = fmaxf(m.x, v0.x); m.y = fmaxf(m.y, v0.y);
    }
    float h0 = tanhf(dc * m.x + b[0]);
    float h1 = tanhf(dc * m.y + b[1]);
    float2 ho; ho.x = h0; ho.y = h1;
    ((float2*)hout)[node] = ho;
    float4 o;
    o.x = h0 * Wc[0] + h1 * Wc[4] + bc[0];
    o.y = h0 * Wc[1] + h1 * Wc[5] + bc[1];
    o.z = h0 * Wc[2] + h1 * Wc[6] + bc[2];
    o.w = h0 * Wc[3] + h1 * Wc[7] + bc[3];
    ((float4*)out)[node] = o;
}

extern "C" void kernel_launch(void* const* d_in, const int* in_sizes, int n_in,
                              void* d_out, int out_size, void* d_ws, size_t ws_size,
                              hipStream_t stream) {
    const float* x  = (const float*)d_in[0];
    const int*   ei = (const int*)d_in[1];
    const int* row = ei;            // edge_index[0] = source
    const int* col = ei + EE;       // edge_index[1] = target
    const float* W1 = (const float*)d_in[2];  const float* b1 = (const float*)d_in[3];
    const float* W2 = (const float*)d_in[4];  const float* b2 = (const float*)d_in[5];
    const float* W3 = (const float*)d_in[6];  const float* b3 = (const float*)d_in[7];
    const float* W4 = (const float*)d_in[8];  const float* b4 = (const float*)d_in[9];
    const float* W5 = (const float*)d_in[10]; const float* b5 = (const float*)d_in[11];
    const float* Wc = (const float*)d_in[12]; const float* bc = (const float*)d_in[13];
    float* out = (float*)d_out;

    // ---- workspace carve ----
    // pairs (25.6 MB) is dead before matmul128_y writes bufB -> alias them.
    char* ws = (char*)d_ws;
    int*          deg        = (int*)(ws + 0);          //    800,000
    float*        dinv       = (float*)(ws + 800000);   //    800,000
    int*          offs       = (int*)(ws + 1600000);    //    800,000
    int*          bbase      = (int*)(ws + 2400000);    //      2,048  (NBKT+1 ints)
    int*          blkhist    = (int*)(ws + 2402048);    //    802,816  (GRID_A*NBKT ints)
    int*          btot       = (int*)(ws + 3204864);    //      2,048
    unsigned int* pairs      = (unsigned int*)(ws + 3206912);   // 25,600,000
    float*        bufB       = (float*)(ws + 3206912);          // 25,600,000 (aliases pairs; y1/y3/y5)
    int*          row_sorted = (int*)(ws + 28806912);           // 25,600,000
    float*        bufA       = (float*)(ws + 54406912);         // 19,200,000 (y2/y4)
    // total: 73,606,912 B

    const int BLK = 256;
    const int gN = (NN + BLK - 1) / BLK;       // 782

    // ---- CSR build: two-level counting sort, LDS atomics only; adjacency band-sorted ----
    count_buckets_kernel<<<GRID_A, BLK_A, 0, stream>>>(col, blkhist);
    scan_cols_kernel<<<NBKT, GRID_A, 0, stream>>>(blkhist, btot);
    scan_btot_kernel<<<1, 512, 0, stream>>>(btot, bbase);
    place_pairs_kernel<<<GRID_A, BLK_A, 0, stream>>>(row, col, blkhist, bbase, pairs);
    bucket_build_kernel<<<NBKT, 512, 0, stream>>>(pairs, bbase, deg, offs, dinv, row_sorted);

    // ---- layer 1 matmul: y1 = dinv * (x @ W1), [N,24] ----
    matmul128_y_kernel<<<gN, BLK, 0, stream>>>(x, W1, dinv, bufB, NN);

    // ---- layer 1 gather + layer-2 matmul fused: y2 [N,12] ----
    {
        constexpr int NPB = 256 / (24 / 4);   // 42 nodes/block
        gather_fused_kernel<24, 12, 4><<<(NN + NPB - 1) / NPB, 256, 0, stream>>>(
            offs, deg, row_sorted, dinv, bufB, b1, W2, bufA);
    }
    // ---- layer 2 gather + layer-3 matmul fused: y3 [N,6] ----
    {
        constexpr int NPB = 256 / (12 / 4);   // 85 nodes/block
        gather_fused_kernel<12, 6, 4><<<(NN + NPB - 1) / NPB, 256, 0, stream>>>(
            offs, deg, row_sorted, dinv, bufA, b2, W3, bufB);
    }
    // ---- layer 3 gather + layer-4 matmul fused: y4 [N,4] ----
    {
        constexpr int NPB = 256 / (6 / 2);    // 85 nodes/block
        gather_fused_kernel<6, 4, 2><<<(NN + NPB - 1) / NPB, 256, 0, stream>>>(
            offs, deg, row_sorted, dinv, bufB, b3, W4, bufA);
    }
    // ---- layer 4 gather + layer-5 matmul fused: y5 [N,2] ----
    gather_fused4_kernel<<<gN, BLK, 0, stream>>>(offs, deg, row_sorted, dinv, bufA, b4, W5, bufB);

    // ---- layer 5 gather + classifier fused: out [N,4], h [N,2] ----
    gather_final_kernel<<<gN, BLK, 0, stream>>>(offs, deg, row_sorted, dinv, bufB, b5, Wc, bc,
                                                out, out + (size_t)NN * 4);
}

// Round 4
// 731.960 us; speedup vs baseline: 1.1596x; 1.0783x over previous
//
#include <hip/hip_runtime.h>
#include <cmath>

#define NN 200000
#define EE 6400000
#define NBKT 391          // ceil(200000 / 512), bucket = col >> 9
#define GRID_A 512        // blocks in phase-A kernels (MUST match scan width)
#define BLK_A 256
#define RB_SHIFT 13       // row band = row >> 13 (8192 rows/band)
#define NRB 25            // ceil(200000 / 8192)

// monotone float<->uint encoding: enc preserves order under unsigned max
__device__ __forceinline__ unsigned int fenc(float f) {
    unsigned int u = __float_as_uint(f);
    return (u & 0x80000000u) ? ~u : (u | 0x80000000u);
}
__device__ __forceinline__ float fdec(unsigned int u) {
    unsigned int v = (u & 0x80000000u) ? (u & 0x7FFFFFFFu) : ~u;
    return __uint_as_float(v);
}

// =============== Phase A: bucket edges by col>>9 (counting sort, LDS atomics only) ===============

__global__ __launch_bounds__(BLK_A) void count_buckets_kernel(const int* __restrict__ col,
                                                              int* __restrict__ blkhist) {
    __shared__ int h[NBKT];
    for (int t = threadIdx.x; t < NBKT; t += BLK_A) h[t] = 0;
    __syncthreads();
    const int4* col4 = (const int4*)col;
    for (int i = blockIdx.x * BLK_A + threadIdx.x; i < EE / 4; i += GRID_A * BLK_A) {
        int4 c = col4[i];
        atomicAdd(&h[c.x >> 9], 1);
        atomicAdd(&h[c.y >> 9], 1);
        atomicAdd(&h[c.z >> 9], 1);
        atomicAdd(&h[c.w >> 9], 1);
    }
    __syncthreads();
    for (int t = threadIdx.x; t < NBKT; t += BLK_A) blkhist[blockIdx.x * NBKT + t] = h[t];
}

__global__ __launch_bounds__(GRID_A) void scan_cols_kernel(int* __restrict__ blkhist,
                                                           int* __restrict__ btot) {
    __shared__ int sc[GRID_A];
    int bkt = blockIdx.x, t = threadIdx.x;
    int v = blkhist[t * NBKT + bkt];
    sc[t] = v;
    __syncthreads();
    for (int off = 1; off < GRID_A; off <<= 1) {
        int add = (t >= off) ? sc[t - off] : 0;
        __syncthreads();
        sc[t] += add;
        __syncthreads();
    }
    blkhist[t * NBKT + bkt] = sc[t] - v;  // exclusive along blocks
    if (t == GRID_A - 1) btot[bkt] = sc[t];
}

__global__ __launch_bounds__(512) void scan_btot_kernel(const int* __restrict__ btot,
                                                        int* __restrict__ bbase) {
    __shared__ int sc[512];
    int t = threadIdx.x;
    int v = (t < NBKT) ? btot[t] : 0;
    sc[t] = v;
    __syncthreads();
    for (int off = 1; off < 512; off <<= 1) {
        int add = (t >= off) ? sc[t - off] : 0;
        __syncthreads();
        sc[t] += add;
        __syncthreads();
    }
    if (t < NBKT) bbase[t] = sc[t] - v;
    if (t == NBKT - 1) bbase[NBKT] = sc[t];  // total = EE
}

// A3: place packed codes (int4 edge loads). code = (col&511)<<18 | row  (row < 2^18)
__global__ __launch_bounds__(BLK_A) void place_pairs_kernel(const int* __restrict__ row,
                                                            const int* __restrict__ col,
                                                            const int* __restrict__ blkhist,
                                                            const int* __restrict__ bbase,
                                                            unsigned int* __restrict__ pairs) {
    __shared__ int cur[NBKT];
    for (int t = threadIdx.x; t < NBKT; t += BLK_A)
        cur[t] = bbase[t] + blkhist[blockIdx.x * NBKT + t];
    __syncthreads();
    const int4* col4 = (const int4*)col;
    const int4* row4 = (const int4*)row;
    for (int i = blockIdx.x * BLK_A + threadIdx.x; i < EE / 4; i += GRID_A * BLK_A) {
        int4 c = col4[i];
        int4 r = row4[i];
        int p0 = atomicAdd(&cur[c.x >> 9], 1);
        pairs[p0] = (unsigned int)r.x | ((unsigned int)(c.x & 511) << 18);
        int p1 = atomicAdd(&cur[c.y >> 9], 1);
        pairs[p1] = (unsigned int)r.y | ((unsigned int)(c.y & 511) << 18);
        int p2 = atomicAdd(&cur[c.z >> 9], 1);
        pairs[p2] = (unsigned int)r.z | ((unsigned int)(c.z & 511) << 18);
        int p3 = atomicAdd(&cur[c.w >> 9], 1);
        pairs[p3] = (unsigned int)r.w | ((unsigned int)(c.w & 511) << 18);
    }
}

// A4: per-bucket counting sort into BAND-MAJOR order (band = row>>RB_SHIFT).
// Output codes[] keeps the (lc<<18)|row packing; bandoffs[b][bb] gives each
// bucket's per-band segment. Also emits dinv.
__global__ __launch_bounds__(512) void bucket_build_band_kernel(const unsigned int* __restrict__ pairs,
                                                                const int* __restrict__ bbase,
                                                                float* __restrict__ dinv,
                                                                unsigned int* __restrict__ codes,
                                                                int* __restrict__ bandoffs) {
    __shared__ int bin[512 * NRB];   // flat band-major: linear n = bb*512 + lc
    __shared__ int sc[512];
    int b = blockIdx.x, tid = threadIdx.x;
    int base = bbase[b], end = bbase[b + 1];
    int node0 = b << 9;
    int nloc = NN - node0; if (nloc > 512) nloc = 512;

    for (int t = tid; t < 512 * NRB; t += 512) bin[t] = 0;
    __syncthreads();
    for (int i = base + tid; i < end; i += 512) {
        unsigned int p = pairs[i];
        int lc = p >> 18;
        int rw = (int)(p & 0x3FFFFu);
        atomicAdd(&bin[(rw >> RB_SHIFT) * 512 + lc], 1);
    }
    __syncthreads();

    // degree -> dinv (read before positions overwrite bins)
    if (tid < nloc) {
        int d = 0;
#pragma unroll
        for (int bb = 0; bb < NRB; ++bb) d += bin[bb * 512 + tid];
        dinv[node0 + tid] = rsqrtf((float)(d + 1));  // +1 self loop
    }
    __syncthreads();

    // exclusive scan of the flat 12800 array: thread t owns linear chunk [t*NRB, t*NRB+NRB)
    int tot = 0;
#pragma unroll
    for (int i = 0; i < NRB; ++i) tot += bin[tid * NRB + i];
    sc[tid] = tot;
    __syncthreads();
    for (int off = 1; off < 512; off <<= 1) {
        int add = (tid >= off) ? sc[tid - off] : 0;
        __syncthreads();
        sc[tid] += add;
        __syncthreads();
    }
    int run = base + sc[tid] - tot;   // global exclusive base of this chunk
#pragma unroll
    for (int i = 0; i < NRB; ++i) {
        int c = bin[tid * NRB + i];
        bin[tid * NRB + i] = run;     // becomes placement cursor
        run += c;
    }
    __syncthreads();

    if (tid < NRB) bandoffs[b * (NRB + 1) + tid] = bin[tid * 512];
    if (tid == 0) bandoffs[b * (NRB + 1) + NRB] = end;
    __syncthreads();

    for (int i = base + tid; i < end; i += 512) {
        unsigned int p = pairs[i];
        int lc = p >> 18;
        int rw = (int)(p & 0x3FFFFu);
        int pos = atomicAdd(&bin[(rw >> RB_SHIFT) * 512 + lc], 1);
        codes[pos] = p;
    }
}

// =============== layer-1 matmul, epilogue premultiplies dinv: y = dinv[i] * (x[i] @ W) ===============
__global__ void matmul128_y_kernel(const float* __restrict__ x, const float* __restrict__ W,
                                   const float* __restrict__ dinv, float* __restrict__ y, int n) {
    __shared__ float Ws[128 * 24];
    for (int t = threadIdx.x; t < 128 * 24; t += blockDim.x) Ws[t] = W[t];
    __syncthreads();
    int i = blockIdx.x * blockDim.x + threadIdx.x;
    if (i >= n) return;
    float acc[24];
#pragma unroll
    for (int j = 0; j < 24; ++j) acc[j] = 0.f;
    const float4* hr = (const float4*)(x + (size_t)i * 128);
#pragma unroll 8
    for (int k4 = 0; k4 < 32; ++k4) {
        float4 hv = hr[k4];
        const float* wk = &Ws[k4 * 4 * 24];
#pragma unroll
        for (int j = 0; j < 24; ++j) acc[j] += hv.x * wk[j];
#pragma unroll
        for (int j = 0; j < 24; ++j) acc[j] += hv.y * wk[24 + j];
#pragma unroll
        for (int j = 0; j < 24; ++j) acc[j] += hv.z * wk[48 + j];
#pragma unroll
        for (int j = 0; j < 24; ++j) acc[j] += hv.w * wk[72 + j];
    }
    float di = dinv[i];
    float4* orow = (float4*)(y + (size_t)i * 24);
#pragma unroll
    for (int q = 0; q < 6; ++q) {
        float4 o;
        o.x = di * acc[q * 4 + 0];
        o.y = di * acc[q * 4 + 1];
        o.z = di * acc[q * 4 + 2];
        o.w = di * acc[q * 4 + 3];
        orow[q] = o;
    }
}

// =============== band-phased bucket gather: max into LDS (uint-encoded), then tanh + matmul ==========
// One block per 512-node bucket; 391 blocks x 512 threads = fully co-resident,
// balanced per-band work -> the whole chip sweeps y band-by-band (~0.8 MB slice
// resident in each XCD L2). Edges are independent parallel units: no dependent
// pointer chase. Guarded LDS atomicMax keeps atomic traffic ~3 wins/32 edges.
template<int DOUT, int DNEXT, bool FINAL>
__global__ __launch_bounds__(512) void gather_band_kernel(const unsigned int* __restrict__ codes,
                                                          const int* __restrict__ bandoffs,
                                                          const float* __restrict__ dinv,
                                                          const float* __restrict__ y,
                                                          const float* __restrict__ bias,
                                                          const float* __restrict__ Wn,
                                                          const float* __restrict__ bcls,
                                                          float* __restrict__ outp,
                                                          float* __restrict__ hout) {
    __shared__ unsigned int acc[512 * DOUT];
    __shared__ float dcs[512];
    __shared__ float Ws[DOUT * DNEXT];
    __shared__ float bs[DOUT];
    const int b0 = blockIdx.x;
    const int node0 = b0 << 9;
    const int nloc = (NN - node0 < 512) ? (NN - node0) : 512;
    const int tid = threadIdx.x;

    if (tid < DOUT * DNEXT) Ws[tid] = Wn[tid];
    if (tid < DOUT) bs[tid] = bias[tid];
    if (tid < nloc) dcs[tid] = dinv[node0 + tid];
    for (int idx = tid; idx < nloc * DOUT; idx += 512)
        acc[idx] = fenc(y[(size_t)node0 * DOUT + idx]);   // self-loop seed
    __syncthreads();

    const int* bo = bandoffs + b0 * (NRB + 1);
#pragma unroll 1
    for (int bb = 0; bb < NRB; ++bb) {
        const int e = bo[bb + 1];
        for (int i = bo[bb] + tid; i < e; i += 512) {
            unsigned int p = codes[i];
            int lc = (int)(p >> 18);
            size_t r = (size_t)(p & 0x3FFFFu);
            unsigned int* a = &acc[lc * DOUT];
            if constexpr (DOUT % 4 == 0) {
                const float4* yr = (const float4*)(y + r * DOUT);
                float4 c[DOUT / 4];
#pragma unroll
                for (int q = 0; q < DOUT / 4; ++q) c[q] = yr[q];
#pragma unroll
                for (int q = 0; q < DOUT / 4; ++q) {
                    unsigned int e0 = fenc(c[q].x), e1 = fenc(c[q].y);
                    unsigned int e2 = fenc(c[q].z), e3 = fenc(c[q].w);
                    if (e0 > a[q * 4 + 0]) atomicMax(&a[q * 4 + 0], e0);
                    if (e1 > a[q * 4 + 1]) atomicMax(&a[q * 4 + 1], e1);
                    if (e2 > a[q * 4 + 2]) atomicMax(&a[q * 4 + 2], e2);
                    if (e3 > a[q * 4 + 3]) atomicMax(&a[q * 4 + 3], e3);
                }
            } else {
                const float2* yr = (const float2*)(y + r * DOUT);
                float2 c[DOUT / 2];
#pragma unroll
                for (int q = 0; q < DOUT / 2; ++q) c[q] = yr[q];
#pragma unroll
                for (int q = 0; q < DOUT / 2; ++q) {
                    unsigned int e0 = fenc(c[q].x), e1 = fenc(c[q].y);
                    if (e0 > a[q * 2 + 0]) atomicMax(&a[q * 2 + 0], e0);
                    if (e1 > a[q * 2 + 1]) atomicMax(&a[q * 2 + 1], e1);
                }
            }
        }
        __syncthreads();   // keep the block (and, statistically, the chip) in one band
    }

    // decode + tanh in place
    float* hsf = (float*)acc;
    for (int idx = tid; idx < nloc * DOUT; idx += 512) {
        int lc = idx / DOUT;
        int f = idx - lc * DOUT;
        hsf[idx] = tanhf(dcs[lc] * fdec(acc[idx]) + bs[f]);
    }
    __syncthreads();

    if constexpr (!FINAL) {
        for (int idx = tid; idx < nloc * DNEXT; idx += 512) {
            int lc = idx / DNEXT;
            int j = idx - lc * DNEXT;
            float a = 0.f;
#pragma unroll
            for (int k = 0; k < DOUT; ++k) a += hsf[lc * DOUT + k] * Ws[k * DNEXT + j];
            outp[(size_t)node0 * DNEXT + idx] = dcs[lc] * a;
        }
    } else {
        for (int lc = tid; lc < nloc; lc += 512) {
            float h0 = hsf[lc * 2], h1 = hsf[lc * 2 + 1];
            float2 ho; ho.x = h0; ho.y = h1;
            ((float2*)hout)[node0 + lc] = ho;
            float4 o;
            o.x = h0 * Ws[0] + h1 * Ws[DNEXT + 0] + bcls[0];
            o.y = h0 * Ws[1] + h1 * Ws[DNEXT + 1] + bcls[1];
            o.z = h0 * Ws[2] + h1 * Ws[DNEXT + 2] + bcls[2];
            o.w = h0 * Ws[3] + h1 * Ws[DNEXT + 3] + bcls[3];
            ((float4*)outp)[node0 + lc] = o;
        }
    }
}

extern "C" void kernel_launch(void* const* d_in, const int* in_sizes, int n_in,
                              void* d_out, int out_size, void* d_ws, size_t ws_size,
                              hipStream_t stream) {
    const float* x  = (const float*)d_in[0];
    const int*   ei = (const int*)d_in[1];
    const int* row = ei;            // edge_index[0] = source
    const int* col = ei + EE;       // edge_index[1] = target
    const float* W1 = (const float*)d_in[2];  const float* b1 = (const float*)d_in[3];
    const float* W2 = (const float*)d_in[4];  const float* b2 = (const float*)d_in[5];
    const float* W3 = (const float*)d_in[6];  const float* b3 = (const float*)d_in[7];
    const float* W4 = (const float*)d_in[8];  const float* b4 = (const float*)d_in[9];
    const float* W5 = (const float*)d_in[10]; const float* b5 = (const float*)d_in[11];
    const float* Wc = (const float*)d_in[12]; const float* bc = (const float*)d_in[13];
    float* out = (float*)d_out;

    // ---- workspace carve ----
    // pairs is dead before matmul128_y writes bufB -> alias them. codes persists all layers.
    char* ws = (char*)d_ws;
    float*        dinv       = (float*)(ws + 0);             //    800,000
    int*          bandoffs   = (int*)(ws + 800000);          //     40,664 (NBKT*(NRB+1) ints) -> pad 40,960
    int*          bbase      = (int*)(ws + 840960);          //      2,048
    int*          btot       = (int*)(ws + 843008);          //      2,048
    int*          blkhist    = (int*)(ws + 845056);          //    802,816  (GRID_A*NBKT ints)
    unsigned int* codes      = (unsigned int*)(ws + 1647872);   // 25,600,000
    unsigned int* pairs      = (unsigned int*)(ws + 27247872);  // 25,600,000
    float*        bufB       = (float*)(ws + 27247872);         // 25,600,000 (aliases pairs; y1/y3/y5)
    float*        bufA       = (float*)(ws + 52847872);         // 19,200,000 (y2/y4)
    // total: 72,047,872 B

    const int BLK = 256;
    const int gN = (NN + BLK - 1) / BLK;       // 782

    // ---- CSR build: two-level counting sort; adjacency emitted band-major per bucket ----
    count_buckets_kernel<<<GRID_A, BLK_A, 0, stream>>>(col, blkhist);
    scan_cols_kernel<<<NBKT, GRID_A, 0, stream>>>(blkhist, btot);
    scan_btot_kernel<<<1, 512, 0, stream>>>(btot, bbase);
    place_pairs_kernel<<<GRID_A, BLK_A, 0, stream>>>(row, col, blkhist, bbase, pairs);
    bucket_build_band_kernel<<<NBKT, 512, 0, stream>>>(pairs, bbase, dinv, codes, bandoffs);

    // ---- layer 1 matmul: y1 = dinv * (x @ W1), [N,24] ----
    matmul128_y_kernel<<<gN, BLK, 0, stream>>>(x, W1, dinv, bufB, NN);

    // ---- layer 1 gather + layer-2 matmul fused: y2 [N,12] ----
    gather_band_kernel<24, 12, false><<<NBKT, 512, 0, stream>>>(
        codes, bandoffs, dinv, bufB, b1, W2, nullptr, bufA, nullptr);
    // ---- layer 2 gather + layer-3 matmul fused: y3 [N,6] ----
    gather_band_kernel<12, 6, false><<<NBKT, 512, 0, stream>>>(
        codes, bandoffs, dinv, bufA, b2, W3, nullptr, bufB, nullptr);
    // ---- layer 3 gather + layer-4 matmul fused: y4 [N,4] ----
    gather_band_kernel<6, 4, false><<<NBKT, 512, 0, stream>>>(
        codes, bandoffs, dinv, bufB, b3, W4, nullptr, bufA, nullptr);
    // ---- layer 4 gather + layer-5 matmul fused: y5 [N,2] ----
    gather_band_kernel<4, 2, false><<<NBKT, 512, 0, stream>>>(
        codes, bandoffs, dinv, bufA, b4, W5, nullptr, bufB, nullptr);
    // ---- layer 5 gather + classifier fused: out [N,4], h [N,2] ----
    gather_band_kernel<2, 4, true><<<NBKT, 512, 0, stream>>>(
        codes, bandoffs, dinv, bufB, b5, Wc, bc, out, out + (size_t)NN * 4);
}

// Round 5
// 722.634 us; speedup vs baseline: 1.1745x; 1.0129x over previous
//
#include <hip/hip_runtime.h>
#include <cmath>

#define NN 200000
#define EE 6400000
#define NBKT 391          // ceil(200000 / 512), bucket = col >> 9
#define GRID_A 512        // blocks in phase-A kernels (MUST match scan width)
#define BLK_A 256
#define RB_SHIFT 13       // row band = row >> 13 (8192 rows/band)
#define NRB 25            // ceil(200000 / 8192)

// monotone float<->uint encoding: enc preserves order under unsigned max
__device__ __forceinline__ unsigned int fenc(float f) {
    unsigned int u = __float_as_uint(f);
    return (u & 0x80000000u) ? ~u : (u | 0x80000000u);
}
__device__ __forceinline__ float fdec(unsigned int u) {
    unsigned int v = (u & 0x80000000u) ? (u & 0x7FFFFFFFu) : ~u;
    return __uint_as_float(v);
}

// =============== Phase A: bucket edges by col>>9 (counting sort, LDS atomics only) ===============

__global__ __launch_bounds__(BLK_A) void count_buckets_kernel(const int* __restrict__ col,
                                                              int* __restrict__ blkhist) {
    __shared__ int h[NBKT];
    for (int t = threadIdx.x; t < NBKT; t += BLK_A) h[t] = 0;
    __syncthreads();
    const int4* col4 = (const int4*)col;
    for (int i = blockIdx.x * BLK_A + threadIdx.x; i < EE / 4; i += GRID_A * BLK_A) {
        int4 c = col4[i];
        atomicAdd(&h[c.x >> 9], 1);
        atomicAdd(&h[c.y >> 9], 1);
        atomicAdd(&h[c.z >> 9], 1);
        atomicAdd(&h[c.w >> 9], 1);
    }
    __syncthreads();
    for (int t = threadIdx.x; t < NBKT; t += BLK_A) blkhist[blockIdx.x * NBKT + t] = h[t];
}

__global__ __launch_bounds__(GRID_A) void scan_cols_kernel(int* __restrict__ blkhist,
                                                           int* __restrict__ btot) {
    __shared__ int sc[GRID_A];
    int bkt = blockIdx.x, t = threadIdx.x;
    int v = blkhist[t * NBKT + bkt];
    sc[t] = v;
    __syncthreads();
    for (int off = 1; off < GRID_A; off <<= 1) {
        int add = (t >= off) ? sc[t - off] : 0;
        __syncthreads();
        sc[t] += add;
        __syncthreads();
    }
    blkhist[t * NBKT + bkt] = sc[t] - v;  // exclusive along blocks
    if (t == GRID_A - 1) btot[bkt] = sc[t];
}

__global__ __launch_bounds__(512) void scan_btot_kernel(const int* __restrict__ btot,
                                                        int* __restrict__ bbase) {
    __shared__ int sc[512];
    int t = threadIdx.x;
    int v = (t < NBKT) ? btot[t] : 0;
    sc[t] = v;
    __syncthreads();
    for (int off = 1; off < 512; off <<= 1) {
        int add = (t >= off) ? sc[t - off] : 0;
        __syncthreads();
        sc[t] += add;
        __syncthreads();
    }
    if (t < NBKT) bbase[t] = sc[t] - v;
    if (t == NBKT - 1) bbase[NBKT] = sc[t];  // total = EE
}

// A3: place packed codes (int4 edge loads). code = (col&511)<<18 | row  (row < 2^18)
__global__ __launch_bounds__(BLK_A) void place_pairs_kernel(const int* __restrict__ row,
                                                            const int* __restrict__ col,
                                                            const int* __restrict__ blkhist,
                                                            const int* __restrict__ bbase,
                                                            unsigned int* __restrict__ pairs) {
    __shared__ int cur[NBKT];
    for (int t = threadIdx.x; t < NBKT; t += BLK_A)
        cur[t] = bbase[t] + blkhist[blockIdx.x * NBKT + t];
    __syncthreads();
    const int4* col4 = (const int4*)col;
    const int4* row4 = (const int4*)row;
    for (int i = blockIdx.x * BLK_A + threadIdx.x; i < EE / 4; i += GRID_A * BLK_A) {
        int4 c = col4[i];
        int4 r = row4[i];
        int p0 = atomicAdd(&cur[c.x >> 9], 1);
        pairs[p0] = (unsigned int)r.x | ((unsigned int)(c.x & 511) << 18);
        int p1 = atomicAdd(&cur[c.y >> 9], 1);
        pairs[p1] = (unsigned int)r.y | ((unsigned int)(c.y & 511) << 18);
        int p2 = atomicAdd(&cur[c.z >> 9], 1);
        pairs[p2] = (unsigned int)r.z | ((unsigned int)(c.z & 511) << 18);
        int p3 = atomicAdd(&cur[c.w >> 9], 1);
        pairs[p3] = (unsigned int)r.w | ((unsigned int)(c.w & 511) << 18);
    }
}

// A4: per-bucket counting sort into BAND-MAJOR order (band = row>>RB_SHIFT).
// Output codes[] keeps the (lc<<18)|row packing; bandoffs[b][bb] gives each
// bucket's per-band segment. Also emits dinv.
__global__ __launch_bounds__(512) void bucket_build_band_kernel(const unsigned int* __restrict__ pairs,
                                                                const int* __restrict__ bbase,
                                                                float* __restrict__ dinv,
                                                                unsigned int* __restrict__ codes,
                                                                int* __restrict__ bandoffs) {
    __shared__ int bin[512 * NRB];   // flat band-major: linear n = bb*512 + lc
    __shared__ int sc[512];
    int b = blockIdx.x, tid = threadIdx.x;
    int base = bbase[b], end = bbase[b + 1];
    int node0 = b << 9;
    int nloc = NN - node0; if (nloc > 512) nloc = 512;

    for (int t = tid; t < 512 * NRB; t += 512) bin[t] = 0;
    __syncthreads();
    for (int i = base + tid; i < end; i += 512) {
        unsigned int p = pairs[i];
        int lc = p >> 18;
        int rw = (int)(p & 0x3FFFFu);
        atomicAdd(&bin[(rw >> RB_SHIFT) * 512 + lc], 1);
    }
    __syncthreads();

    // degree -> dinv (read before positions overwrite bins)
    if (tid < nloc) {
        int d = 0;
#pragma unroll
        for (int bb = 0; bb < NRB; ++bb) d += bin[bb * 512 + tid];
        dinv[node0 + tid] = rsqrtf((float)(d + 1));  // +1 self loop
    }
    __syncthreads();

    // exclusive scan of the flat 12800 array: thread t owns linear chunk [t*NRB, t*NRB+NRB)
    int tot = 0;
#pragma unroll
    for (int i = 0; i < NRB; ++i) tot += bin[tid * NRB + i];
    sc[tid] = tot;
    __syncthreads();
    for (int off = 1; off < 512; off <<= 1) {
        int add = (tid >= off) ? sc[tid - off] : 0;
        __syncthreads();
        sc[tid] += add;
        __syncthreads();
    }
    int run = base + sc[tid] - tot;   // global exclusive base of this chunk
#pragma unroll
    for (int i = 0; i < NRB; ++i) {
        int c = bin[tid * NRB + i];
        bin[tid * NRB + i] = run;     // becomes placement cursor
        run += c;
    }
    __syncthreads();

    if (tid < NRB) bandoffs[b * (NRB + 1) + tid] = bin[tid * 512];
    if (tid == 0) bandoffs[b * (NRB + 1) + NRB] = end;
    __syncthreads();

    for (int i = base + tid; i < end; i += 512) {
        unsigned int p = pairs[i];
        int lc = p >> 18;
        int rw = (int)(p & 0x3FFFFu);
        int pos = atomicAdd(&bin[(rw >> RB_SHIFT) * 512 + lc], 1);
        codes[pos] = p;
    }
}

// =============== layer-1 matmul, epilogue premultiplies dinv: y = dinv[i] * (x[i] @ W) ===============
__global__ void matmul128_y_kernel(const float* __restrict__ x, const float* __restrict__ W,
                                   const float* __restrict__ dinv, float* __restrict__ y, int n) {
    __shared__ float Ws[128 * 24];
    for (int t = threadIdx.x; t < 128 * 24; t += blockDim.x) Ws[t] = W[t];
    __syncthreads();
    int i = blockIdx.x * blockDim.x + threadIdx.x;
    if (i >= n) return;
    float acc[24];
#pragma unroll
    for (int j = 0; j < 24; ++j) acc[j] = 0.f;
    const float4* hr = (const float4*)(x + (size_t)i * 128);
#pragma unroll 8
    for (int k4 = 0; k4 < 32; ++k4) {
        float4 hv = hr[k4];
        const float* wk = &Ws[k4 * 4 * 24];
#pragma unroll
        for (int j = 0; j < 24; ++j) acc[j] += hv.x * wk[j];
#pragma unroll
        for (int j = 0; j < 24; ++j) acc[j] += hv.y * wk[24 + j];
#pragma unroll
        for (int j = 0; j < 24; ++j) acc[j] += hv.z * wk[48 + j];
#pragma unroll
        for (int j = 0; j < 24; ++j) acc[j] += hv.w * wk[72 + j];
    }
    float di = dinv[i];
    float4* orow = (float4*)(y + (size_t)i * 24);
#pragma unroll
    for (int q = 0; q < 6; ++q) {
        float4 o;
        o.x = di * acc[q * 4 + 0];
        o.y = di * acc[q * 4 + 1];
        o.z = di * acc[q * 4 + 2];
        o.w = di * acc[q * 4 + 3];
        orow[q] = o;
    }
}

// =============== band-phased bucket gather: max into LDS (uint-encoded), then tanh + matmul ==========
// One block per 512-node bucket; 391 blocks x 512 threads = fully co-resident,
// balanced per-band work -> the whole chip sweeps y band-by-band (~0.8 MB slice
// resident in each XCD L2). Per-node LDS stride is padded to ODD (gcd(ST,32)=1):
// with DOUT=24 the bank of acc[lc*24+q] hit only 4 distinct banks (gcd(24,32)=8,
// ~16-way conflicts, 2.7e7 conflict cycles in r4); odd stride spreads random lc
// across all 32 banks (~2 lanes/bank for wave64 = free).
template<int DOUT, int DNEXT, bool FINAL>
__global__ __launch_bounds__(512) void gather_band_kernel(const unsigned int* __restrict__ codes,
                                                          const int* __restrict__ bandoffs,
                                                          const float* __restrict__ dinv,
                                                          const float* __restrict__ y,
                                                          const float* __restrict__ bias,
                                                          const float* __restrict__ Wn,
                                                          const float* __restrict__ bcls,
                                                          float* __restrict__ outp,
                                                          float* __restrict__ hout) {
    constexpr int ST = DOUT + 1;           // odd stride -> conflict-free random access
    __shared__ unsigned int acc[512 * ST];
    __shared__ float dcs[512];
    __shared__ float Ws[DOUT * DNEXT];
    __shared__ float bs[DOUT];
    const int b0 = blockIdx.x;
    const int node0 = b0 << 9;
    const int nloc = (NN - node0 < 512) ? (NN - node0) : 512;
    const int tid = threadIdx.x;

    if (tid < DOUT * DNEXT) Ws[tid] = Wn[tid];
    if (tid < DOUT) bs[tid] = bias[tid];
    if (tid < nloc) dcs[tid] = dinv[node0 + tid];
    for (int idx = tid; idx < nloc * DOUT; idx += 512) {
        int lc = idx / DOUT;
        int f  = idx - lc * DOUT;
        acc[lc * ST + f] = fenc(y[(size_t)node0 * DOUT + idx]);   // self-loop seed
    }
    __syncthreads();

    const int* bo = bandoffs + b0 * (NRB + 1);
#pragma unroll 1
    for (int bb = 0; bb < NRB; ++bb) {
        const int e = bo[bb + 1];
        for (int i = bo[bb] + tid; i < e; i += 512) {
            unsigned int p = codes[i];
            int lc = (int)(p >> 18);
            size_t r = (size_t)(p & 0x3FFFFu);
            unsigned int* a = &acc[lc * ST];
            if constexpr (DOUT % 4 == 0) {
                const float4* yr = (const float4*)(y + r * DOUT);
                float4 c[DOUT / 4];
#pragma unroll
                for (int q = 0; q < DOUT / 4; ++q) c[q] = yr[q];
#pragma unroll
                for (int q = 0; q < DOUT / 4; ++q) {
                    unsigned int e0 = fenc(c[q].x), e1 = fenc(c[q].y);
                    unsigned int e2 = fenc(c[q].z), e3 = fenc(c[q].w);
                    if (e0 > a[q * 4 + 0]) atomicMax(&a[q * 4 + 0], e0);
                    if (e1 > a[q * 4 + 1]) atomicMax(&a[q * 4 + 1], e1);
                    if (e2 > a[q * 4 + 2]) atomicMax(&a[q * 4 + 2], e2);
                    if (e3 > a[q * 4 + 3]) atomicMax(&a[q * 4 + 3], e3);
                }
            } else {
                const float2* yr = (const float2*)(y + r * DOUT);
                float2 c[DOUT / 2];
#pragma unroll
                for (int q = 0; q < DOUT / 2; ++q) c[q] = yr[q];
#pragma unroll
                for (int q = 0; q < DOUT / 2; ++q) {
                    unsigned int e0 = fenc(c[q].x), e1 = fenc(c[q].y);
                    if (e0 > a[q * 2 + 0]) atomicMax(&a[q * 2 + 0], e0);
                    if (e1 > a[q * 2 + 1]) atomicMax(&a[q * 2 + 1], e1);
                }
            }
        }
        __syncthreads();   // keep the block (and, statistically, the chip) in one band
    }

    // decode + tanh in place (float bits through the same padded layout)
    float* hsf = (float*)acc;
    for (int idx = tid; idx < nloc * DOUT; idx += 512) {
        int lc = idx / DOUT;
        int f  = idx - lc * DOUT;
        hsf[lc * ST + f] = tanhf(dcs[lc] * fdec(acc[lc * ST + f]) + bs[f]);
    }
    __syncthreads();

    if constexpr (!FINAL) {
        for (int idx = tid; idx < nloc * DNEXT; idx += 512) {
            int lc = idx / DNEXT;
            int j = idx - lc * DNEXT;
            float a = 0.f;
#pragma unroll
            for (int k = 0; k < DOUT; ++k) a += hsf[lc * ST + k] * Ws[k * DNEXT + j];
            outp[(size_t)node0 * DNEXT + idx] = dcs[lc] * a;
        }
    } else {
        for (int lc = tid; lc < nloc; lc += 512) {
            float h0 = hsf[lc * ST], h1 = hsf[lc * ST + 1];
            float2 ho; ho.x = h0; ho.y = h1;
            ((float2*)hout)[node0 + lc] = ho;
            float4 o;
            o.x = h0 * Ws[0] + h1 * Ws[DNEXT + 0] + bcls[0];
            o.y = h0 * Ws[1] + h1 * Ws[DNEXT + 1] + bcls[1];
            o.z = h0 * Ws[2] + h1 * Ws[DNEXT + 2] + bcls[2];
            o.w = h0 * Ws[3] + h1 * Ws[DNEXT + 3] + bcls[3];
            ((float4*)outp)[node0 + lc] = o;
        }
    }
}

extern "C" void kernel_launch(void* const* d_in, const int* in_sizes, int n_in,
                              void* d_out, int out_size, void* d_ws, size_t ws_size,
                              hipStream_t stream) {
    const float* x  = (const float*)d_in[0];
    const int*   ei = (const int*)d_in[1];
    const int* row = ei;            // edge_index[0] = source
    const int* col = ei + EE;       // edge_index[1] = target
    const float* W1 = (const float*)d_in[2];  const float* b1 = (const float*)d_in[3];
    const float* W2 = (const float*)d_in[4];  const float* b2 = (const float*)d_in[5];
    const float* W3 = (const float*)d_in[6];  const float* b3 = (const float*)d_in[7];
    const float* W4 = (const float*)d_in[8];  const float* b4 = (const float*)d_in[9];
    const float* W5 = (const float*)d_in[10]; const float* b5 = (const float*)d_in[11];
    const float* Wc = (const float*)d_in[12]; const float* bc = (const float*)d_in[13];
    float* out = (float*)d_out;

    // ---- workspace carve ----
    // pairs is dead before matmul128_y writes bufB -> alias them. codes persists all layers.
    char* ws = (char*)d_ws;
    float*        dinv       = (float*)(ws + 0);             //    800,000
    int*          bandoffs   = (int*)(ws + 800000);          //     40,664 (NBKT*(NRB+1) ints) -> pad 40,960
    int*          bbase      = (int*)(ws + 840960);          //      2,048
    int*          btot       = (int*)(ws + 843008);          //      2,048
    int*          blkhist    = (int*)(ws + 845056);          //    802,816  (GRID_A*NBKT ints)
    unsigned int* codes      = (unsigned int*)(ws + 1647872);   // 25,600,000
    unsigned int* pairs      = (unsigned int*)(ws + 27247872);  // 25,600,000
    float*        bufB       = (float*)(ws + 27247872);         // 25,600,000 (aliases pairs; y1/y3/y5)
    float*        bufA       = (float*)(ws + 52847872);         // 19,200,000 (y2/y4)
    // total: 72,047,872 B

    const int BLK = 256;
    const int gN = (NN + BLK - 1) / BLK;       // 782

    // ---- CSR build: two-level counting sort; adjacency emitted band-major per bucket ----
    count_buckets_kernel<<<GRID_A, BLK_A, 0, stream>>>(col, blkhist);
    scan_cols_kernel<<<NBKT, GRID_A, 0, stream>>>(blkhist, btot);
    scan_btot_kernel<<<1, 512, 0, stream>>>(btot, bbase);
    place_pairs_kernel<<<GRID_A, BLK_A, 0, stream>>>(row, col, blkhist, bbase, pairs);
    bucket_build_band_kernel<<<NBKT, 512, 0, stream>>>(pairs, bbase, dinv, codes, bandoffs);

    // ---- layer 1 matmul: y1 = dinv * (x @ W1), [N,24] ----
    matmul128_y_kernel<<<gN, BLK, 0, stream>>>(x, W1, dinv, bufB, NN);

    // ---- layer 1 gather + layer-2 matmul fused: y2 [N,12] ----
    gather_band_kernel<24, 12, false><<<NBKT, 512, 0, stream>>>(
        codes, bandoffs, dinv, bufB, b1, W2, nullptr, bufA, nullptr);
    // ---- layer 2 gather + layer-3 matmul fused: y3 [N,6] ----
    gather_band_kernel<12, 6, false><<<NBKT, 512, 0, stream>>>(
        codes, bandoffs, dinv, bufA, b2, W3, nullptr, bufB, nullptr);
    // ---- layer 3 gather + layer-4 matmul fused: y4 [N,4] ----
    gather_band_kernel<6, 4, false><<<NBKT, 512, 0, stream>>>(
        codes, bandoffs, dinv, bufB, b3, W4, nullptr, bufA, nullptr);
    // ---- layer 4 gather + layer-5 matmul fused: y5 [N,2] ----
    gather_band_kernel<4, 2, false><<<NBKT, 512, 0, stream>>>(
        codes, bandoffs, dinv, bufA, b4, W5, nullptr, bufB, nullptr);
    // ---- layer 5 gather + classifier fused: out [N,4], h [N,2] ----
    gather_band_kernel<2, 4, true><<<NBKT, 512, 0, stream>>>(
        codes, bandoffs, dinv, bufB, b5, Wc, bc, out, out + (size_t)NN * 4);
}